// Round 8
// baseline (747.843 us; speedup 1.0000x reference)
//
#include <hip/hip_runtime.h>
#include <cstdint>

#define NNZ   100000
#define CBINS 16
#define HD    1024
#define WD    1024
#define CIN   128
#define CH    128
#define QMAX  (NNZ * (CBINS - 1))
#define PCAP  8192   // per-tap pair-list capacity (expected ~5000, 46 sigma margin)

// ============================ threefry2x32 (JAX) ============================
struct Key { uint32_t a, b; };

__device__ __forceinline__ uint32_t rotl32(uint32_t v, int r) {
  return (v << r) | (v >> (32 - r));
}

__device__ __forceinline__ void tf_block(uint32_t k0, uint32_t k1,
                                         uint32_t x0, uint32_t x1,
                                         uint32_t& o0, uint32_t& o1) {
  uint32_t ks2 = k0 ^ k1 ^ 0x1BD11BDAu;
  x0 += k0; x1 += k1;
#define TF_RND(r) { x0 += x1; x1 = rotl32(x1, r); x1 ^= x0; }
  TF_RND(13) TF_RND(15) TF_RND(26) TF_RND(6)
  x0 += k1;  x1 += ks2 + 1u;
  TF_RND(17) TF_RND(29) TF_RND(16) TF_RND(24)
  x0 += ks2; x1 += k0 + 2u;
  TF_RND(13) TF_RND(15) TF_RND(26) TF_RND(6)
  x0 += k0;  x1 += k1 + 3u;
  TF_RND(17) TF_RND(29) TF_RND(16) TF_RND(24)
  x0 += k1;  x1 += ks2 + 4u;
  TF_RND(13) TF_RND(15) TF_RND(26) TF_RND(6)
  x0 += ks2; x1 += k0 + 5u;
#undef TF_RND
  o0 = x0; o1 = x1;
}

__device__ __forceinline__ Key tf_key(Key k, uint32_t chi, uint32_t clo) {
  Key r; tf_block(k.a, k.b, chi, clo, r.a, r.b); return r;
}

__device__ __forceinline__ uint32_t random_bits32(Key k) {
  uint32_t a, b; tf_block(k.a, k.b, 0u, 0u, a, b); return a ^ b;
}

// ============================ JAX float samplers ============================
__device__ __forceinline__ float bits_to_u01(uint32_t bits) {
  uint32_t fb = (bits >> 9) | 0x3F800000u;
  return __uint_as_float(fb) - 1.0f;
}

__device__ float erfinv32(float x) {
#pragma clang fp contract(off)
  float w = -log1pf(-(x * x));
  float p;
  if (w < 5.0f) {
    w = w - 2.5f;
    p = 2.81022636e-08f;
    p = 3.43273939e-07f  + p * w;
    p = -3.5233877e-06f  + p * w;
    p = -4.39150654e-06f + p * w;
    p = 0.00021858087f   + p * w;
    p = -0.00125372503f  + p * w;
    p = -0.00417768164f  + p * w;
    p = 0.246640727f     + p * w;
    p = 1.50140941f      + p * w;
  } else {
    w = sqrtf(w) - 3.0f;
    p = -0.000200214257f;
    p = 0.000100950558f  + p * w;
    p = 0.00134934322f   + p * w;
    p = -0.00367342844f  + p * w;
    p = 0.00573950773f   + p * w;
    p = -0.0076224613f   + p * w;
    p = 0.00943887047f   + p * w;
    p = 1.00167406f      + p * w;
    p = 2.83297682f      + p * w;
  }
  return p * x;
}

__device__ __forceinline__ float uniform01(Key k) {
  return bits_to_u01(random_bits32(k));
}

__device__ __forceinline__ float normal_f32(Key k) {
#pragma clang fp contract(off)
  const float LO = -0x1.fffffep-1f;  // nextafter(-1, 0)
  float f = bits_to_u01(random_bits32(k));
  float u = f * 2.0f + LO;
  u = fmaxf(LO, u);
  return 1.4142135623730951f * erfinv32(u);
}

// _gamma_one(key, alpha, log_space=True) — Marsaglia–Tsang, JAX trace order
__device__ float loggamma_one(Key key, float alpha_orig) {
#pragma clang fp contract(off)
  bool boost = (alpha_orig >= 1.0f);
  float alpha = boost ? alpha_orig : (alpha_orig + 1.0f);
  const float OT = 0.3333333333333333f;
  float d = alpha - OT;
  float c = OT / sqrtf(d);

  Key knext = tf_key(key, 0u, 0u);
  Key ksub  = tf_key(key, 0u, 1u);
  float u_boost = uniform01(ksub);

  float X = 0.0f, V = 1.0f, U = 2.0f;
  while (true) {
    bool c1 = U >= (1.0f - 0.0331f * (X * X));
    bool c2 = logf(U) >= (X * 0.5f + d * ((1.0f - V) + logf(V)));
    if (!(c1 && c2)) break;
    Key kcur = knext;
    knext    = tf_key(kcur, 0u, 0u);
    Key xk   = tf_key(kcur, 0u, 1u);
    Key Uk   = tf_key(kcur, 0u, 2u);
    float x = 0.0f, v = -1.0f;
    while (v <= 0.0f) {
      Key nxk = tf_key(xk, 0u, 0u);
      Key sk  = tf_key(xk, 0u, 1u);
      xk = nxk;
      x = normal_f32(sk);
      v = 1.0f + x * c;
    }
    X = x * x;
    V = (v * v) * v;
    U = uniform01(Uk);
  }
  float log_samples = logf(d) + logf(V);
  float log_boost = 0.0f;
  if (!boost && u_boost != 0.0f)
    log_boost = logf(u_boost) * (1.0f / alpha_orig);
  return log_samples + log_boost;
}

__device__ float beta_sample(Key ka, Key kb, uint32_t q, float a, float b) {
#pragma clang fp contract(off)
  Key ga = tf_key(ka, 0u, q);
  Key gb = tf_key(kb, 0u, q);
  float la = loggamma_one(ga, a);
  float lb = loggamma_one(gb, b);
  float lm = fmaxf(la, lb);
  float ea = expf(la - lm);
  float eb = expf(lb - lm);
  return ea / (ea + eb);
}

// ============================ pipeline kernels ============================

// Exact replica of jax.lax.associative_scan's add association for n=16.
__device__ __forceinline__ void ascan16(const float* a, float* out) {
  float r[8], r2[4], r3[2];
#pragma unroll
  for (int i = 0; i < 8; ++i) r[i] = a[2 * i] + a[2 * i + 1];
#pragma unroll
  for (int i = 0; i < 4; ++i) r2[i] = r[2 * i] + r[2 * i + 1];
  r3[0] = r2[0] + r2[1];
  r3[1] = r2[2] + r2[3];
  float r4 = r3[0] + r3[1];
  float s3[2] = {r3[0], r4};
  float s2[4] = {r2[0], s3[0], s3[0] + r2[2], s3[1]};
  float sr[8] = {r[0],          s2[0],
                 s2[0] + r[2],  s2[1],
                 s2[1] + r[4],  s2[2],
                 s2[2] + r[6],  s2[3]};
  out[0] = a[0];
#pragma unroll
  for (int i = 0; i < 8; ++i) out[2 * i + 1] = sr[i];
#pragma unroll
  for (int i = 0; i < 7; ++i) out[2 * i + 2] = sr[i] + a[2 * i + 2];
}

__global__ __launch_bounds__(256)
void counts_kernel(const float* __restrict__ occ_values,
                   const int* __restrict__ occ_idx,
                   int* __restrict__ counts,
                   int* __restrict__ flatall) {
  int i = blockIdx.x * 256 + threadIdx.x;
  if (i >= NNZ) return;
  const float4* vp = (const float4*)(occ_values + (size_t)i * CBINS);
  float4 q0 = vp[0], q1 = vp[1], q2 = vp[2], q3 = vp[3];
  float v[16] = {q0.x,q0.y,q0.z,q0.w, q1.x,q1.y,q1.z,q1.w,
                 q2.x,q2.y,q2.z,q2.w, q3.x,q3.y,q3.z,q3.w};
  float m = v[0];
#pragma unroll
  for (int k = 1; k < 16; ++k) m = fmaxf(m, v[k]);
  float e[16];
#pragma unroll
  for (int k = 0; k < 16; ++k) e[k] = expf(v[k] - m);
  float s = 0.0f;
#pragma unroll
  for (int k = 0; k < 16; ++k) s += e[k];
  float p[16], cdf[16];
#pragma unroll
  for (int k = 0; k < 16; ++k) p[k] = e[k] / s;
  ascan16(p, cdf);
  int cnt = 0; bool found = false;
#pragma unroll
  for (int k = 0; k < 16; ++k) {
    if (!found && cdf[k] > 0.95f) { found = true; cnt = k; }
  }
  counts[i] = found ? cnt : 0;
  int b_ = occ_idx[i], i_ = occ_idx[NNZ + i], j_ = occ_idx[2 * NNZ + i];
  flatall[i] = (b_ * HD + i_) * WD + j_;
}

#define SCAN_B 1024
__global__ __launch_bounds__(SCAN_B)
void scan_block_kernel(const int* __restrict__ counts, int* __restrict__ cum,
                       int* __restrict__ bsums) {
  __shared__ int sh[SCAN_B];
  int t = threadIdx.x;
  int i = blockIdx.x * SCAN_B + t;
  sh[t] = (i < NNZ) ? counts[i] : 0;
  __syncthreads();
  for (int off = 1; off < SCAN_B; off <<= 1) {
    int add = (t >= off) ? sh[t - off] : 0;
    __syncthreads();
    sh[t] += add;
    __syncthreads();
  }
  if (i < NNZ) cum[i] = sh[t];
  if (t == SCAN_B - 1) bsums[blockIdx.x] = sh[t];
}

__global__ void scan_sums_kernel(int* bsums, int nblocks) {
  __shared__ int sh[128];
  int t = threadIdx.x;
  sh[t] = (t < nblocks) ? bsums[t] : 0;
  __syncthreads();
  for (int off = 1; off < 128; off <<= 1) {
    int add = (t >= off) ? sh[t - off] : 0;
    __syncthreads();
    sh[t] += add;
    __syncthreads();
  }
  if (t < nblocks) bsums[t] = sh[t];
}

__global__ __launch_bounds__(SCAN_B)
void scan_add_kernel(int* cum, const int* __restrict__ bsums) {
  int b = blockIdx.x;
  if (b == 0) return;
  int i = b * SCAN_B + threadIdx.x;
  if (i < NNZ) cum[i] += bsums[b - 1];
}

__device__ __forceinline__ int find_site(const int* __restrict__ flatall, int tval) {
  int lo = 0, hi = NNZ;
  while (lo < hi) {
    int mid = (lo + hi) >> 1;
    if (flatall[mid] < tval) lo = mid + 1; else hi = mid;
  }
  return (lo < NNZ && flatall[lo] == tval) ? lo : -1;
}

// Per-site off-center neighbors -> per-tap pair lists + pairidx[s*8+m].
// List order is nondeterministic (atomic append) but irrelevant: each pair
// gets a private output slot; the head reduces in ascending-m order.
__global__ __launch_bounds__(256)
void neighbors_kernel(const int* __restrict__ occ_idx,
                      const int* __restrict__ flatall,
                      int* __restrict__ pl_r,     // [8][PCAP] neighbor row
                      int* __restrict__ ncnt,     // [8]
                      int* __restrict__ pairidx) {// [NNZ][8] slot or -1
  int s = blockIdx.x * 256 + threadIdx.x;
  if (s >= NNZ) return;
  int b_ = occ_idx[s], i_ = occ_idx[NNZ + s], j_ = occ_idx[2 * NNZ + s];
  int m = 0;
#pragma unroll
  for (int di = -1; di <= 1; ++di) {
#pragma unroll
    for (int dj = -1; dj <= 1; ++dj) {
      if (di == 0 && dj == 0) continue;
      int ni = i_ + di, nj = j_ + dj, r = -1;
      if ((unsigned)ni < HD && (unsigned)nj < WD)
        r = find_site(flatall, (b_ * HD + ni) * WD + nj);
      int idx = -1;
      if (r >= 0) {
        int slot = atomicAdd(&ncnt[m], 1);
        if (slot < PCAP) {
          pl_r[m * PCAP + slot] = r;
          idx = m * PCAP + slot;
        }
      }
      pairidx[(size_t)s * 8 + m] = idx;
      ++m;
    }
  }
}

// Expand ragged repeat: srcmap[q] = owning site for q in [cum[s]-counts[s], cum[s])
__global__ __launch_bounds__(256)
void scatter_src_kernel(const int* __restrict__ counts,
                        const int* __restrict__ cum,
                        int* __restrict__ srcmap) {
  int s = blockIdx.x * 256 + threadIdx.x;
  if (s >= NNZ) return;
  int e = cum[s], c = counts[s];
  for (int q = e - c; q < e; ++q) srcmap[q] = s;
}

// Dense center-tap GEMM: h[site] = b1 + pv[site] @ w1[center].
// Identical association to round-5 phase 1 (b1 init, ascending k).
#define TSITES 64
__global__ __launch_bounds__(256)
void conv_center_kernel(const float* __restrict__ pv,
                        const float* __restrict__ w1,
                        const float* __restrict__ b1,
                        float* __restrict__ h) {
  __shared__ float Wsh[32 * CH];   // 16 KB
  int base = blockIdx.x * TSITES;
  int t = threadIdx.x;
  int ts = t >> 5, to = t & 31;    // thread tile: 8 sites (s8*8+ts) x 4 cols

  float acc[8][4];
  {
    float4 bv = *(const float4*)(b1 + to * 4);
#pragma unroll
    for (int s8 = 0; s8 < 8; ++s8) {
      acc[s8][0] = bv.x; acc[s8][1] = bv.y; acc[s8][2] = bv.z; acc[s8][3] = bv.w;
    }
  }

  const float* prow[8];
#pragma unroll
  for (int s8 = 0; s8 < 8; ++s8) {
    int site = base + s8 * 8 + ts;
    if (site > NNZ - 1) site = NNZ - 1;
    prow[s8] = pv + (size_t)site * CIN;
  }

  const float* wc = w1 + 4 * CIN * CH;  // center tap
  for (int k0 = 0; k0 < CIN; k0 += 32) {
    __syncthreads();  // WAR on Wsh
    {
      const float4* srcw = (const float4*)(wc + (size_t)k0 * CH);
      float4* dstw = (float4*)Wsh;
#pragma unroll
      for (int rep = 0; rep < 4; ++rep) dstw[t + rep * 256] = srcw[t + rep * 256];
    }
    __syncthreads();
#pragma unroll
    for (int kk = 0; kk < 32; kk += 4) {
      float4 wq0 = ((const float4*)(Wsh + (kk + 0) * CH))[to];
      float4 wq1 = ((const float4*)(Wsh + (kk + 1) * CH))[to];
      float4 wq2 = ((const float4*)(Wsh + (kk + 2) * CH))[to];
      float4 wq3 = ((const float4*)(Wsh + (kk + 3) * CH))[to];
#pragma unroll
      for (int s8 = 0; s8 < 8; ++s8) {
        float4 a4 = *(const float4*)(prow[s8] + k0 + kk);
        acc[s8][0] += a4.x * wq0.x; acc[s8][1] += a4.x * wq0.y;
        acc[s8][2] += a4.x * wq0.z; acc[s8][3] += a4.x * wq0.w;
        acc[s8][0] += a4.y * wq1.x; acc[s8][1] += a4.y * wq1.y;
        acc[s8][2] += a4.y * wq1.z; acc[s8][3] += a4.y * wq1.w;
        acc[s8][0] += a4.z * wq2.x; acc[s8][1] += a4.z * wq2.y;
        acc[s8][2] += a4.z * wq2.z; acc[s8][3] += a4.z * wq2.w;
        acc[s8][0] += a4.w * wq3.x; acc[s8][1] += a4.w * wq3.y;
        acc[s8][2] += a4.w * wq3.z; acc[s8][3] += a4.w * wq3.w;
      }
    }
  }

#pragma unroll
  for (int s8 = 0; s8 < 8; ++s8) {
    int site = base + s8 * 8 + ts;
    if (site < NNZ)
      *(float4*)(h + (size_t)site * CH + 4 * to) =
          make_float4(acc[s8][0], acc[s8][1], acc[s8][2], acc[s8][3]);
  }
}

// Tap-batched pair GEMM: block <-> one tap, W[tap] staged once in LDS.
// One wave per pair; lane l owns cols (2l, 2l+1); K ascending — inner
// association identical to round-7's corr loop, computed as a partial sum
// into a private slot (reduced in ascending-m order by head_kernel).
__global__ __launch_bounds__(256)
void pair_kernel(const float* __restrict__ pv,
                 const float* __restrict__ w1,
                 const int* __restrict__ pl_r,
                 const int* __restrict__ ncnt,
                 float* __restrict__ pairout) {
  __shared__ float Wsh[CIN * CH];  // 64 KB
  int tm = blockIdx.x & 7;
  int tap = (tm < 4) ? tm : tm + 1;
  {
    const float4* src = (const float4*)(w1 + (size_t)tap * CIN * CH);
    float4* dst = (float4*)Wsh;
    for (int i = threadIdx.x; i < CIN * CH / 4; i += 256) dst[i] = src[i];
  }
  __syncthreads();
  int n = ncnt[tm];
  if (n > PCAP) n = PCAP;
  int w = threadIdx.x >> 6, l = threadIdx.x & 63;
  int nb = gridDim.x >> 3;
  for (int e = (blockIdx.x >> 3) * 4 + w; e < n; e += nb * 4) {
    int r = pl_r[tm * PCAP + e];
    const float* pr = pv + (size_t)r * CIN;
    float a0 = 0.0f, a1 = 0.0f;
    for (int k = 0; k < CIN; k += 4) {
      float4 pq = *(const float4*)(pr + k);
      float2 w0 = *(const float2*)(Wsh + (k + 0) * CH + 2 * l);
      float2 w1v = *(const float2*)(Wsh + (k + 1) * CH + 2 * l);
      float2 w2v = *(const float2*)(Wsh + (k + 2) * CH + 2 * l);
      float2 w3v = *(const float2*)(Wsh + (k + 3) * CH + 2 * l);
      a0 += pq.x * w0.x;  a1 += pq.x * w0.y;
      a0 += pq.y * w1v.x; a1 += pq.y * w1v.y;
      a0 += pq.z * w2v.x; a1 += pq.z * w2v.y;
      a0 += pq.w * w3v.x; a1 += pq.w * w3v.y;
    }
    *(float2*)(pairout + (size_t)(tm * PCAP + e) * CH + 2 * l) =
        make_float2(a0, a1);
  }
}

// Head: h_final = center + pair partials (ascending m), then
// logp[site][j] = b2[j] + sum_o relu(h[o]) * w2[o][j] (serial ascending o).
#define HP 132
__global__ __launch_bounds__(256)
void head_kernel(const float* __restrict__ h,
                 const int* __restrict__ pairidx,
                 const float* __restrict__ pairout,
                 const float* __restrict__ w2,
                 const float* __restrict__ b2,
                 float* __restrict__ logp) {
  __shared__ float hs[TSITES * HP];  // 33 KB
  int base = blockIdx.x * TSITES;
  int t = threadIdx.x;
#pragma unroll
  for (int rep = 0; rep < 8; ++rep) {
    int idx = t + rep * 256;   // float4 index; 32 float4 per row
    int s = idx >> 5, c = idx & 31;
    int site = base + s;
    if (site > NNZ - 1) site = NNZ - 1;
    float4 v = *(const float4*)(h + (size_t)site * CH + 4 * c);
    *(float4*)(hs + s * HP + 4 * c) = v;
  }
  __syncthreads();
  // add pair partials: thread t -> site s = t>>2, col group g = t&3 (32 cols)
  {
    int s = t >> 2, g = t & 3;
    int site = base + s;
    if (site < NNZ) {
      float* hr = hs + s * HP + g * 32;
#pragma unroll
      for (int m = 0; m < 8; ++m) {
        int idx = pairidx[(size_t)site * 8 + m];
        if (idx < 0) continue;
        const float* po = pairout + (size_t)idx * CH + g * 32;
#pragma unroll
        for (int c = 0; c < 32; c += 4) {
          float4 v = *(const float4*)(po + c);
          hr[c + 0] += v.x; hr[c + 1] += v.y;
          hr[c + 2] += v.z; hr[c + 3] += v.w;
        }
      }
    }
  }
  __syncthreads();
  int s = t & 63, j = t >> 6;
  int site = base + s;
  if (site < NNZ) {
    const float* hr = hs + s * HP;
    float sum = 0.0f;
    for (int o = 0; o < CH; o += 2) {
      float2 hv = *(const float2*)(hr + o);
      sum += fmaxf(hv.x, 0.f) * w2[(o + 0) * 4 + j];
      sum += fmaxf(hv.y, 0.f) * w2[(o + 1) * 4 + j];
    }
    logp[(size_t)site * 4 + j] = sum + b2[j];
  }
}

// per-query: srcmap lookup, gather indices+params, Beta rsample
__global__ __launch_bounds__(256)
void query_kernel(const int* __restrict__ occ_idx,
                  const int* __restrict__ cum,
                  const int* __restrict__ srcmap,
                  const float* __restrict__ logp,
                  float* __restrict__ out_idx,   // [QMAX, 3] as float
                  float* __restrict__ out_off) { // [QMAX, 2]
  int q = blockIdx.x * 256 + threadIdx.x;
  if (q >= QMAX) return;
  int total = cum[NNZ - 1];
  if (q >= total) {
    out_idx[(size_t)q * 3 + 0] = 0.0f;
    out_idx[(size_t)q * 3 + 1] = 0.0f;
    out_idx[(size_t)q * 3 + 2] = 0.0f;
    out_off[(size_t)q * 2 + 0] = 0.0f;
    out_off[(size_t)q * 2 + 1] = 0.0f;
    return;
  }
  int src = srcmap[q];
  out_idx[(size_t)q * 3 + 0] = (float)occ_idx[src];
  out_idx[(size_t)q * 3 + 1] = (float)occ_idx[NNZ + src];
  out_idx[(size_t)q * 3 + 2] = (float)occ_idx[2 * NNZ + src];

  float4 lp = *(const float4*)(logp + (size_t)src * 4);
  float p0 = expf(lp.x), p1 = expf(lp.y), p2 = expf(lp.z), p3 = expf(lp.w);

  Key root{0u, 42u};
  Key k1  = tf_key(root, 0u, 0u);
  Key k2  = tf_key(root, 0u, 1u);
  Key kxa = tf_key(k1, 0u, 0u);
  Key kxb = tf_key(k1, 0u, 1u);
  Key kya = tf_key(k2, 0u, 0u);
  Key kyb = tf_key(k2, 0u, 1u);

  float x = beta_sample(kxa, kxb, (uint32_t)q, p0, p1);
  float y = beta_sample(kya, kyb, (uint32_t)q, p2, p3);
  out_off[(size_t)q * 2 + 0] = x;
  out_off[(size_t)q * 2 + 1] = y;
}

// ============================ launch ============================
extern "C" void kernel_launch(void* const* d_in, const int* in_sizes, int n_in,
                              void* d_out, int out_size, void* d_ws, size_t ws_size,
                              hipStream_t stream) {
  const float* occ_values = (const float*)d_in[0];
  const int*   occ_idx    = (const int*)d_in[1];
  const float* pv         = (const float*)d_in[2];
  const float* w1         = (const float*)d_in[3];
  const float* b1         = (const float*)d_in[4];
  const float* w2         = (const float*)d_in[5];
  const float* b2         = (const float*)d_in[6];

  char* ws = (char*)d_ws;
  auto alignup = [](size_t x) { return (x + 255) & ~(size_t)255; };
  size_t o = 0;
  int* counts   = (int*)(ws + o); o += alignup((size_t)NNZ * 4);
  int* cum      = (int*)(ws + o); o += alignup((size_t)NNZ * 4);
  int* flatall  = (int*)(ws + o); o += alignup((size_t)NNZ * 4);
  int* bsums    = (int*)(ws + o); o += alignup(128 * 4);
  float* logp   = (float*)(ws + o); o += alignup((size_t)NNZ * 4 * sizeof(float));
  int* pairidx  = (int*)(ws + o); o += alignup((size_t)NNZ * 8 * 4);
  int* srcmap   = (int*)(ws + o); o += alignup((size_t)QMAX * 4);
  int* pl_r     = (int*)(ws + o); o += alignup((size_t)8 * PCAP * 4);
  int* ncnt     = (int*)(ws + o); o += alignup(256);
  float* h      = (float*)(ws + o); o += alignup((size_t)NNZ * CH * sizeof(float));
  float* pairout= (float*)(ws + o); o += alignup((size_t)8 * PCAP * CH * sizeof(float));

  float* out_idx = (float*)d_out;
  float* out_off = out_idx + (size_t)QMAX * 3;

  counts_kernel<<<(NNZ + 255) / 256, 256, 0, stream>>>(occ_values, occ_idx,
                                                       counts, flatall);
  int nsb = (NNZ + SCAN_B - 1) / SCAN_B;  // 98
  scan_block_kernel<<<nsb, SCAN_B, 0, stream>>>(counts, cum, bsums);
  scan_sums_kernel<<<1, 128, 0, stream>>>(bsums, nsb);
  scan_add_kernel<<<nsb, SCAN_B, 0, stream>>>(cum, bsums);
  hipMemsetAsync(ncnt, 0, 32, stream);
  neighbors_kernel<<<(NNZ + 255) / 256, 256, 0, stream>>>(occ_idx, flatall,
                                                          pl_r, ncnt, pairidx);
  scatter_src_kernel<<<(NNZ + 255) / 256, 256, 0, stream>>>(counts, cum, srcmap);
  conv_center_kernel<<<(NNZ + TSITES - 1) / TSITES, 256, 0, stream>>>(
      pv, w1, b1, h);
  pair_kernel<<<1024, 256, 0, stream>>>(pv, w1, pl_r, ncnt, pairout);
  head_kernel<<<(NNZ + TSITES - 1) / TSITES, 256, 0, stream>>>(
      h, pairidx, pairout, w2, b2, logp);
  query_kernel<<<(QMAX + 255) / 256, 256, 0, stream>>>(occ_idx, cum, srcmap,
                                                       logp, out_idx, out_off);
}

// Round 9
// 628.128 us; speedup vs baseline: 1.1906x; 1.1906x over previous
//
#include <hip/hip_runtime.h>
#include <cstdint>

#define NNZ   100000
#define CBINS 16
#define HD    1024
#define WD    1024
#define CIN   128
#define CH    128
#define QMAX  (NNZ * (CBINS - 1))

// ============================ threefry2x32 (JAX) ============================
struct Key { uint32_t a, b; };

__device__ __forceinline__ uint32_t rotl32(uint32_t v, int r) {
  return (v << r) | (v >> (32 - r));
}

__device__ __forceinline__ void tf_block(uint32_t k0, uint32_t k1,
                                         uint32_t x0, uint32_t x1,
                                         uint32_t& o0, uint32_t& o1) {
  uint32_t ks2 = k0 ^ k1 ^ 0x1BD11BDAu;
  x0 += k0; x1 += k1;
#define TF_RND(r) { x0 += x1; x1 = rotl32(x1, r); x1 ^= x0; }
  TF_RND(13) TF_RND(15) TF_RND(26) TF_RND(6)
  x0 += k1;  x1 += ks2 + 1u;
  TF_RND(17) TF_RND(29) TF_RND(16) TF_RND(24)
  x0 += ks2; x1 += k0 + 2u;
  TF_RND(13) TF_RND(15) TF_RND(26) TF_RND(6)
  x0 += k0;  x1 += k1 + 3u;
  TF_RND(17) TF_RND(29) TF_RND(16) TF_RND(24)
  x0 += k1;  x1 += ks2 + 4u;
  TF_RND(13) TF_RND(15) TF_RND(26) TF_RND(6)
  x0 += ks2; x1 += k0 + 5u;
#undef TF_RND
  o0 = x0; o1 = x1;
}

__device__ __forceinline__ Key tf_key(Key k, uint32_t chi, uint32_t clo) {
  Key r; tf_block(k.a, k.b, chi, clo, r.a, r.b); return r;
}

__device__ __forceinline__ uint32_t random_bits32(Key k) {
  uint32_t a, b; tf_block(k.a, k.b, 0u, 0u, a, b); return a ^ b;
}

// compile-time threefry for the fixed key schedule of jax.random.key(42)
constexpr uint32_t rotlc(uint32_t v, int r) { return (v << r) | (v >> (32 - r)); }
constexpr Key tf_key_c(Key k, uint32_t c0, uint32_t c1) {
  uint32_t k0 = k.a, k1 = k.b, ks2 = k0 ^ k1 ^ 0x1BD11BDAu;
  uint32_t x0 = c0 + k0, x1 = c1 + k1;
  const int r1[4] = {13, 15, 26, 6}, r2[4] = {17, 29, 16, 24};
  for (int i = 0; i < 4; ++i) { x0 += x1; x1 = rotlc(x1, r1[i]); x1 ^= x0; }
  x0 += k1;  x1 += ks2 + 1u;
  for (int i = 0; i < 4; ++i) { x0 += x1; x1 = rotlc(x1, r2[i]); x1 ^= x0; }
  x0 += ks2; x1 += k0 + 2u;
  for (int i = 0; i < 4; ++i) { x0 += x1; x1 = rotlc(x1, r1[i]); x1 ^= x0; }
  x0 += k0;  x1 += k1 + 3u;
  for (int i = 0; i < 4; ++i) { x0 += x1; x1 = rotlc(x1, r2[i]); x1 ^= x0; }
  x0 += k1;  x1 += ks2 + 4u;
  for (int i = 0; i < 4; ++i) { x0 += x1; x1 = rotlc(x1, r1[i]); x1 ^= x0; }
  x0 += ks2; x1 += k0 + 5u;
  return Key{x0, x1};
}
constexpr Key ROOTK{0u, 42u};
constexpr Key K1C  = tf_key_c(ROOTK, 0u, 0u);
constexpr Key K2C  = tf_key_c(ROOTK, 0u, 1u);
constexpr Key KXA  = tf_key_c(K1C, 0u, 0u);
constexpr Key KXB  = tf_key_c(K1C, 0u, 1u);
constexpr Key KYA  = tf_key_c(K2C, 0u, 0u);
constexpr Key KYB  = tf_key_c(K2C, 0u, 1u);

// ============================ JAX float samplers ============================
__device__ __forceinline__ float bits_to_u01(uint32_t bits) {
  uint32_t fb = (bits >> 9) | 0x3F800000u;
  return __uint_as_float(fb) - 1.0f;
}

__device__ float erfinv32(float x) {
#pragma clang fp contract(off)
  float w = -log1pf(-(x * x));
  float p;
  if (w < 5.0f) {
    w = w - 2.5f;
    p = 2.81022636e-08f;
    p = 3.43273939e-07f  + p * w;
    p = -3.5233877e-06f  + p * w;
    p = -4.39150654e-06f + p * w;
    p = 0.00021858087f   + p * w;
    p = -0.00125372503f  + p * w;
    p = -0.00417768164f  + p * w;
    p = 0.246640727f     + p * w;
    p = 1.50140941f      + p * w;
  } else {
    w = sqrtf(w) - 3.0f;
    p = -0.000200214257f;
    p = 0.000100950558f  + p * w;
    p = 0.00134934322f   + p * w;
    p = -0.00367342844f  + p * w;
    p = 0.00573950773f   + p * w;
    p = -0.0076224613f   + p * w;
    p = 0.00943887047f   + p * w;
    p = 1.00167406f      + p * w;
    p = 2.83297682f      + p * w;
  }
  return p * x;
}

__device__ __forceinline__ float uniform01(Key k) {
  return bits_to_u01(random_bits32(k));
}

__device__ __forceinline__ float normal_f32(Key k) {
#pragma clang fp contract(off)
  const float LO = -0x1.fffffep-1f;  // nextafter(-1, 0)
  float f = bits_to_u01(random_bits32(k));
  float u = f * 2.0f + LO;
  u = fmaxf(LO, u);
  return 1.4142135623730951f * erfinv32(u);
}

// ---- Marsaglia–Tsang log-gamma as a resumable state machine (JAX trace) ----
struct GState { Key knext; float d, c, boost; };

// one rejection iteration; true if accepted (result valid)
__device__ bool gamma_iter(GState& st, float& result) {
#pragma clang fp contract(off)
  Key kcur = st.knext;
  st.knext = tf_key(kcur, 0u, 0u);
  Key xk   = tf_key(kcur, 0u, 1u);
  Key Uk   = tf_key(kcur, 0u, 2u);
  float x = 0.0f, v = -1.0f;
  while (v <= 0.0f) {
    Key nxk = tf_key(xk, 0u, 0u);
    Key sk  = tf_key(xk, 0u, 1u);
    xk = nxk;
    x = normal_f32(sk);
    v = 1.0f + x * st.c;
  }
  float X = x * x;
  float V = (v * v) * v;
  float U = uniform01(Uk);
  bool c1 = U >= (1.0f - 0.0331f * (X * X));
  bool c2 = logf(U) >= (X * 0.5f + st.d * ((1.0f - V) + logf(V)));
  if (!(c1 && c2)) {
    result = (logf(st.d) + logf(V)) + st.boost;
    return true;
  }
  return false;
}

// setup + first iteration (the initial (0,1,2) state always enters the loop)
__device__ bool gamma_first(Key gkey, float alpha_orig, float& result,
                            GState& st) {
#pragma clang fp contract(off)
  bool boost = (alpha_orig >= 1.0f);
  float alpha = boost ? alpha_orig : (alpha_orig + 1.0f);
  const float OT = 0.3333333333333333f;
  st.d = alpha - OT;
  st.c = OT / sqrtf(st.d);
  st.knext = tf_key(gkey, 0u, 0u);
  Key ksub = tf_key(gkey, 0u, 1u);
  float u_boost = uniform01(ksub);
  st.boost = 0.0f;
  if (!boost && u_boost != 0.0f)
    st.boost = logf(u_boost) * (1.0f / alpha_orig);
  return gamma_iter(st, result);
}

// ============================ pipeline kernels ============================

// Exact replica of jax.lax.associative_scan's add association for n=16.
__device__ __forceinline__ void ascan16(const float* a, float* out) {
  float r[8], r2[4], r3[2];
#pragma unroll
  for (int i = 0; i < 8; ++i) r[i] = a[2 * i] + a[2 * i + 1];
#pragma unroll
  for (int i = 0; i < 4; ++i) r2[i] = r[2 * i] + r[2 * i + 1];
  r3[0] = r2[0] + r2[1];
  r3[1] = r2[2] + r2[3];
  float r4 = r3[0] + r3[1];
  float s3[2] = {r3[0], r4};
  float s2[4] = {r2[0], s3[0], s3[0] + r2[2], s3[1]};
  float sr[8] = {r[0],          s2[0],
                 s2[0] + r[2],  s2[1],
                 s2[1] + r[4],  s2[2],
                 s2[2] + r[6],  s2[3]};
  out[0] = a[0];
#pragma unroll
  for (int i = 0; i < 8; ++i) out[2 * i + 1] = sr[i];
#pragma unroll
  for (int i = 0; i < 7; ++i) out[2 * i + 2] = sr[i] + a[2 * i + 2];
}

__global__ __launch_bounds__(256)
void counts_kernel(const float* __restrict__ occ_values,
                   const int* __restrict__ occ_idx,
                   int* __restrict__ counts,
                   int* __restrict__ flatall) {
  int i = blockIdx.x * 256 + threadIdx.x;
  if (i >= NNZ) return;
  const float4* vp = (const float4*)(occ_values + (size_t)i * CBINS);
  float4 q0 = vp[0], q1 = vp[1], q2 = vp[2], q3 = vp[3];
  float v[16] = {q0.x,q0.y,q0.z,q0.w, q1.x,q1.y,q1.z,q1.w,
                 q2.x,q2.y,q2.z,q2.w, q3.x,q3.y,q3.z,q3.w};
  float m = v[0];
#pragma unroll
  for (int k = 1; k < 16; ++k) m = fmaxf(m, v[k]);
  float e[16];
#pragma unroll
  for (int k = 0; k < 16; ++k) e[k] = expf(v[k] - m);
  float s = 0.0f;
#pragma unroll
  for (int k = 0; k < 16; ++k) s += e[k];
  float p[16], cdf[16];
#pragma unroll
  for (int k = 0; k < 16; ++k) p[k] = e[k] / s;
  ascan16(p, cdf);
  int cnt = 0; bool found = false;
#pragma unroll
  for (int k = 0; k < 16; ++k) {
    if (!found && cdf[k] > 0.95f) { found = true; cnt = k; }
  }
  counts[i] = found ? cnt : 0;
  int b_ = occ_idx[i], i_ = occ_idx[NNZ + i], j_ = occ_idx[2 * NNZ + i];
  flatall[i] = (b_ * HD + i_) * WD + j_;
}

#define SCAN_B 1024
__global__ __launch_bounds__(SCAN_B)
void scan_block_kernel(const int* __restrict__ counts, int* __restrict__ cum,
                       int* __restrict__ bsums) {
  __shared__ int sh[SCAN_B];
  int t = threadIdx.x;
  int i = blockIdx.x * SCAN_B + t;
  sh[t] = (i < NNZ) ? counts[i] : 0;
  __syncthreads();
  for (int off = 1; off < SCAN_B; off <<= 1) {
    int add = (t >= off) ? sh[t - off] : 0;
    __syncthreads();
    sh[t] += add;
    __syncthreads();
  }
  if (i < NNZ) cum[i] = sh[t];
  if (t == SCAN_B - 1) bsums[blockIdx.x] = sh[t];
}

__global__ void scan_sums_kernel(int* bsums, int nblocks) {
  __shared__ int sh[128];
  int t = threadIdx.x;
  sh[t] = (t < nblocks) ? bsums[t] : 0;
  __syncthreads();
  for (int off = 1; off < 128; off <<= 1) {
    int add = (t >= off) ? sh[t - off] : 0;
    __syncthreads();
    sh[t] += add;
    __syncthreads();
  }
  if (t < nblocks) bsums[t] = sh[t];
}

__global__ __launch_bounds__(SCAN_B)
void scan_add_kernel(int* cum, const int* __restrict__ bsums) {
  int b = blockIdx.x;
  if (b == 0) return;
  int i = b * SCAN_B + threadIdx.x;
  if (i < NNZ) cum[i] += bsums[b - 1];
}

__device__ __forceinline__ int find_site(const int* __restrict__ flatall, int tval) {
  int lo = 0, hi = NNZ;
  while (lo < hi) {
    int mid = (lo + hi) >> 1;
    if (flatall[mid] < tval) lo = mid + 1; else hi = mid;
  }
  return (lo < NNZ && flatall[lo] == tval) ? lo : -1;
}

// Per-site off-center neighbor rows + global active-site list (round-7 form).
__global__ __launch_bounds__(256)
void neighbors_kernel(const int* __restrict__ occ_idx,
                      const int* __restrict__ flatall,
                      int* __restrict__ rlist,
                      int* __restrict__ asl,
                      int* __restrict__ nact) {
  int s = blockIdx.x * 256 + threadIdx.x;
  if (s >= NNZ) return;
  int b_ = occ_idx[s], i_ = occ_idx[NNZ + s], j_ = occ_idx[2 * NNZ + s];
  int m = 0;
  bool any = false;
#pragma unroll
  for (int di = -1; di <= 1; ++di) {
#pragma unroll
    for (int dj = -1; dj <= 1; ++dj) {
      if (di == 0 && dj == 0) continue;
      int ni = i_ + di, nj = j_ + dj, r = -1;
      if ((unsigned)ni < HD && (unsigned)nj < WD)
        r = find_site(flatall, (b_ * HD + ni) * WD + nj);
      rlist[(size_t)s * 8 + m] = r;
      any |= (r >= 0);
      ++m;
    }
  }
  if (any) {
    int slot = atomicAdd(nact, 1);
    asl[slot] = s;
  }
}

__global__ __launch_bounds__(256)
void scatter_src_kernel(const int* __restrict__ counts,
                        const int* __restrict__ cum,
                        int* __restrict__ srcmap) {
  int s = blockIdx.x * 256 + threadIdx.x;
  if (s >= NNZ) return;
  int e = cum[s], c = counts[s];
  for (int q = e - c; q < e; ++q) srcmap[q] = s;
}

// Dense center-tap GEMM (round-7 form, association unchanged).
#define TSITES 64
__global__ __launch_bounds__(256)
void conv_center_kernel(const float* __restrict__ pv,
                        const float* __restrict__ w1,
                        const float* __restrict__ b1,
                        float* __restrict__ h) {
  __shared__ float Wsh[32 * CH];   // 16 KB
  int base = blockIdx.x * TSITES;
  int t = threadIdx.x;
  int ts = t >> 5, to = t & 31;

  float acc[8][4];
  {
    float4 bv = *(const float4*)(b1 + to * 4);
#pragma unroll
    for (int s8 = 0; s8 < 8; ++s8) {
      acc[s8][0] = bv.x; acc[s8][1] = bv.y; acc[s8][2] = bv.z; acc[s8][3] = bv.w;
    }
  }

  const float* prow[8];
#pragma unroll
  for (int s8 = 0; s8 < 8; ++s8) {
    int site = base + s8 * 8 + ts;
    if (site > NNZ - 1) site = NNZ - 1;
    prow[s8] = pv + (size_t)site * CIN;
  }

  const float* wc = w1 + 4 * CIN * CH;  // center tap
  for (int k0 = 0; k0 < CIN; k0 += 32) {
    __syncthreads();
    {
      const float4* srcw = (const float4*)(wc + (size_t)k0 * CH);
      float4* dstw = (float4*)Wsh;
#pragma unroll
      for (int rep = 0; rep < 4; ++rep) dstw[t + rep * 256] = srcw[t + rep * 256];
    }
    __syncthreads();
#pragma unroll
    for (int kk = 0; kk < 32; kk += 4) {
      float4 wq0 = ((const float4*)(Wsh + (kk + 0) * CH))[to];
      float4 wq1 = ((const float4*)(Wsh + (kk + 1) * CH))[to];
      float4 wq2 = ((const float4*)(Wsh + (kk + 2) * CH))[to];
      float4 wq3 = ((const float4*)(Wsh + (kk + 3) * CH))[to];
#pragma unroll
      for (int s8 = 0; s8 < 8; ++s8) {
        float4 a4 = *(const float4*)(prow[s8] + k0 + kk);
        acc[s8][0] += a4.x * wq0.x; acc[s8][1] += a4.x * wq0.y;
        acc[s8][2] += a4.x * wq0.z; acc[s8][3] += a4.x * wq0.w;
        acc[s8][0] += a4.y * wq1.x; acc[s8][1] += a4.y * wq1.y;
        acc[s8][2] += a4.y * wq1.z; acc[s8][3] += a4.y * wq1.w;
        acc[s8][0] += a4.z * wq2.x; acc[s8][1] += a4.z * wq2.y;
        acc[s8][2] += a4.z * wq2.z; acc[s8][3] += a4.z * wq2.w;
        acc[s8][0] += a4.w * wq3.x; acc[s8][1] += a4.w * wq3.y;
        acc[s8][2] += a4.w * wq3.z; acc[s8][3] += a4.w * wq3.w;
      }
    }
  }

#pragma unroll
  for (int s8 = 0; s8 < 8; ++s8) {
    int site = base + s8 * 8 + ts;
    if (site < NNZ)
      *(float4*)(h + (size_t)site * CH + 4 * to) =
          make_float4(acc[s8][0], acc[s8][1], acc[s8][2], acc[s8][3]);
  }
}

// Sparse off-center corrections (round-7 form; association unchanged).
__global__ __launch_bounds__(256)
void conv_corr_kernel(const float* __restrict__ pv,
                      const float* __restrict__ w1,
                      const int* __restrict__ rlist,
                      const int* __restrict__ asl,
                      const int* __restrict__ nact,
                      float* __restrict__ h) {
  int t = threadIdx.x;
  int l = t & 63;
  int wave = (blockIdx.x << 2) + (t >> 6);
  int nwaves = gridDim.x << 2;
  int n = *nact;
  for (int e = wave; e < n; e += nwaves) {
    int s = asl[e];
    float* hr = h + (size_t)s * CH;
    float2 hv = *(const float2*)(hr + 2 * l);
    float ha = hv.x, hb = hv.y;
#pragma unroll
    for (int m = 0; m < 8; ++m) {
      int r = rlist[(size_t)s * 8 + m];
      if (r < 0) continue;
      int tap = (m < 4) ? m : m + 1;
      const float* wt = w1 + (size_t)tap * CIN * CH + 2 * l;
      const float* pr = pv + (size_t)r * CIN;
#pragma unroll 8
      for (int k = 0; k < CIN; k += 4) {
        float4 pq = *(const float4*)(pr + k);
        float2 wv0 = *(const float2*)(wt + (k + 0) * CH);
        float2 wv1 = *(const float2*)(wt + (k + 1) * CH);
        float2 wv2 = *(const float2*)(wt + (k + 2) * CH);
        float2 wv3 = *(const float2*)(wt + (k + 3) * CH);
        ha += pq.x * wv0.x; hb += pq.x * wv0.y;
        ha += pq.y * wv1.x; hb += pq.y * wv1.y;
        ha += pq.z * wv2.x; hb += pq.z * wv2.y;
        ha += pq.w * wv3.x; hb += pq.w * wv3.y;
      }
    }
    *(float2*)(hr + 2 * l) = make_float2(ha, hb);
  }
}

// Head (round-7 form).
#define HP 132
__global__ __launch_bounds__(256)
void head_kernel(const float* __restrict__ h,
                 const float* __restrict__ w2,
                 const float* __restrict__ b2,
                 float* __restrict__ logp) {
  __shared__ float hs[TSITES * HP];  // 33 KB
  int base = blockIdx.x * TSITES;
  int t = threadIdx.x;
#pragma unroll
  for (int rep = 0; rep < 8; ++rep) {
    int idx = t + rep * 256;
    int s = idx >> 5, c = idx & 31;
    int site = base + s;
    if (site > NNZ - 1) site = NNZ - 1;
    float4 v = *(const float4*)(h + (size_t)site * CH + 4 * c);
    *(float4*)(hs + s * HP + 4 * c) = v;
  }
  __syncthreads();
  int s = t & 63, j = t >> 6;
  int site = base + s;
  if (site < NNZ) {
    const float* hr = hs + s * HP;
    float sum = 0.0f;
    for (int o = 0; o < CH; o += 2) {
      float2 hv = *(const float2*)(hr + o);
      sum += fmaxf(hv.x, 0.f) * w2[(o + 0) * 4 + j];
      sum += fmaxf(hv.y, 0.f) * w2[(o + 1) * 4 + j];
    }
    logp[(size_t)site * 4 + j] = sum + b2[j];
  }
}

// per-query Beta rsample with block-level straggler repacking.
// Iteration 1 of every gamma runs uniformly (initial state always enters the
// loop); the ~4% rejections carry their (knext,d,c,boost) state into an LDS
// queue drained in dense rounds. RNG trace is bit-identical to the serial
// version (state machine is self-contained).
struct QEntry { uint32_t ka, kb; float d, c, boost; int dest; };

__global__ __launch_bounds__(256)
void query_kernel(const int* __restrict__ occ_idx,
                  const int* __restrict__ cum,
                  const int* __restrict__ srcmap,
                  const float* __restrict__ logp,
                  float* __restrict__ out_idx,   // [QMAX, 3] as float
                  float* __restrict__ out_off) { // [QMAX, 2]
  __shared__ QEntry queue[1024];   // 24 KB
  __shared__ float res[1024];      // 4 KB
  __shared__ int qn;
  int t = threadIdx.x;
  if (t == 0) qn = 0;
  int q = blockIdx.x * 256 + t;
  bool inrange = q < QMAX;
  int total = cum[NNZ - 1];
  bool active = inrange && (q < total);

  float alpha[4] = {1.0f, 1.0f, 1.0f, 1.0f};
  if (active) {
    int src = srcmap[q];
    out_idx[(size_t)q * 3 + 0] = (float)occ_idx[src];
    out_idx[(size_t)q * 3 + 1] = (float)occ_idx[NNZ + src];
    out_idx[(size_t)q * 3 + 2] = (float)occ_idx[2 * NNZ + src];
    float4 lp = *(const float4*)(logp + (size_t)src * 4);
    alpha[0] = expf(lp.x); alpha[1] = expf(lp.y);
    alpha[2] = expf(lp.z); alpha[3] = expf(lp.w);
  } else if (inrange) {
    out_idx[(size_t)q * 3 + 0] = 0.0f;
    out_idx[(size_t)q * 3 + 1] = 0.0f;
    out_idx[(size_t)q * 3 + 2] = 0.0f;
    out_off[(size_t)q * 2 + 0] = 0.0f;
    out_off[(size_t)q * 2 + 1] = 0.0f;
  }
  __syncthreads();  // qn init visible

  if (active) {
    const Key gkeys[4] = {KXA, KXB, KYA, KYB};
#pragma unroll
    for (int g = 0; g < 4; ++g) {
      Key gk = tf_key(gkeys[g], 0u, (uint32_t)q);
      float r; GState st;
      if (gamma_first(gk, alpha[g], r, st)) {
        res[t * 4 + g] = r;
      } else {
        int slot = atomicAdd(&qn, 1);
        queue[slot] = QEntry{st.knext.a, st.knext.b, st.d, st.c, st.boost,
                             t * 4 + g};
      }
    }
  }
  __syncthreads();

  int n = qn;
  while (n > 0) {   // n uniform across block (read after barrier)
    QEntry my[4]; int myn = 0;
    for (int i = t; i < n; i += 256) my[myn++] = queue[i];
    __syncthreads();           // all reads done before overwrite
    if (t == 0) qn = 0;
    __syncthreads();
    for (int j = 0; j < myn; ++j) {
      GState st; st.knext = Key{my[j].ka, my[j].kb};
      st.d = my[j].d; st.c = my[j].c; st.boost = my[j].boost;
      float r;
      if (gamma_iter(st, r)) {
        res[my[j].dest] = r;
      } else {
        int slot = atomicAdd(&qn, 1);
        queue[slot] = QEntry{st.knext.a, st.knext.b, st.d, st.c, st.boost,
                             my[j].dest};
      }
    }
    __syncthreads();
    n = qn;
  }

  if (active) {
#pragma clang fp contract(off)
    float la = res[t * 4 + 0], lb = res[t * 4 + 1];
    float lm = fmaxf(la, lb);
    float ea = expf(la - lm), eb = expf(lb - lm);
    float x = ea / (ea + eb);
    float lc = res[t * 4 + 2], ld = res[t * 4 + 3];
    float lm2 = fmaxf(lc, ld);
    float ec = expf(lc - lm2), ed = expf(ld - lm2);
    float y = ec / (ec + ed);
    out_off[(size_t)q * 2 + 0] = x;
    out_off[(size_t)q * 2 + 1] = y;
  }
}

// ============================ launch ============================
extern "C" void kernel_launch(void* const* d_in, const int* in_sizes, int n_in,
                              void* d_out, int out_size, void* d_ws, size_t ws_size,
                              hipStream_t stream) {
  const float* occ_values = (const float*)d_in[0];
  const int*   occ_idx    = (const int*)d_in[1];
  const float* pv         = (const float*)d_in[2];
  const float* w1         = (const float*)d_in[3];
  const float* b1         = (const float*)d_in[4];
  const float* w2         = (const float*)d_in[5];
  const float* b2         = (const float*)d_in[6];

  char* ws = (char*)d_ws;
  auto alignup = [](size_t x) { return (x + 255) & ~(size_t)255; };
  size_t o = 0;
  int* counts  = (int*)(ws + o); o += alignup((size_t)NNZ * 4);
  int* cum     = (int*)(ws + o); o += alignup((size_t)NNZ * 4);
  int* flatall = (int*)(ws + o); o += alignup((size_t)NNZ * 4);
  int* bsums   = (int*)(ws + o); o += alignup(128 * 4);
  float* logp  = (float*)(ws + o); o += alignup((size_t)NNZ * 4 * sizeof(float));
  int* rlist   = (int*)(ws + o); o += alignup((size_t)NNZ * 8 * 4);
  int* srcmap  = (int*)(ws + o); o += alignup((size_t)QMAX * 4);
  int* asl     = (int*)(ws + o); o += alignup((size_t)NNZ * 4);
  int* nact    = (int*)(ws + o); o += alignup(256);
  float* h     = (float*)(ws + o); o += alignup((size_t)NNZ * CH * sizeof(float));

  float* out_idx = (float*)d_out;
  float* out_off = out_idx + (size_t)QMAX * 3;

  counts_kernel<<<(NNZ + 255) / 256, 256, 0, stream>>>(occ_values, occ_idx,
                                                       counts, flatall);
  int nsb = (NNZ + SCAN_B - 1) / SCAN_B;  // 98
  scan_block_kernel<<<nsb, SCAN_B, 0, stream>>>(counts, cum, bsums);
  scan_sums_kernel<<<1, 128, 0, stream>>>(bsums, nsb);
  scan_add_kernel<<<nsb, SCAN_B, 0, stream>>>(cum, bsums);
  hipMemsetAsync(nact, 0, 4, stream);
  neighbors_kernel<<<(NNZ + 255) / 256, 256, 0, stream>>>(occ_idx, flatall,
                                                          rlist, asl, nact);
  scatter_src_kernel<<<(NNZ + 255) / 256, 256, 0, stream>>>(counts, cum, srcmap);
  conv_center_kernel<<<(NNZ + TSITES - 1) / TSITES, 256, 0, stream>>>(
      pv, w1, b1, h);
  conv_corr_kernel<<<2048, 256, 0, stream>>>(pv, w1, rlist, asl, nact, h);
  head_kernel<<<(NNZ + TSITES - 1) / TSITES, 256, 0, stream>>>(h, w2, b2, logp);
  query_kernel<<<(QMAX + 255) / 256, 256, 0, stream>>>(occ_idx, cum, srcmap,
                                                       logp, out_idx, out_off);
}